// Round 9
// baseline (253.869 us; speedup 1.0000x reference)
//
#include <hip/hip_runtime.h>
#include <stdint.h>

#define FP8_MAX 448.0f
#define GBLK 512                 // GEMM blocks = 2/CU x 256 CU (co-resident)
#define KBLK 16                  // blocks 0..15 also do k amax+pack
#define CTR_TARGET (GBLK + KBLK)

typedef __attribute__((ext_vector_type(4))) float f32x4;
typedef long long ll;

// flax fp8_ops.compute_scale: sf = fp8_max/amax with fallbacks (qdq multiplier).
__device__ __forceinline__ float scale_factor(float amax, float prev_scale) {
    float sf = FP8_MAX / amax;
    if (!(amax > 0.0f) || !isfinite(amax)) sf = 1.0f / prev_scale;
    return sf;
}

__device__ __forceinline__ unsigned pack4_fp8(float a, float b, float c, float d) {
    int v = __builtin_amdgcn_cvt_pk_fp8_f32(a, b, 0, false);
    v = __builtin_amdgcn_cvt_pk_fp8_f32(c, d, v, true);
    return (unsigned)v;
}

__device__ __forceinline__ float amax4(f32x4 v, float m) {
    float a0 = fmaxf(__builtin_fabsf(v.x), __builtin_fabsf(v.y));
    float a1 = fmaxf(__builtin_fabsf(v.z), __builtin_fabsf(v.w));
    return fmaxf(m, fmaxf(a0, a1));
}

// ---------------------------------------------------------------------------
// Fused: x-load (once, pinned, into regs) -> local amax -> grid spin-barrier
// (all 512 blocks co-resident at 2/CU) -> global scale -> in-reg quantize ->
// LDS (swizzled, ONE barrier) -> 4x(frag reads + 32 MFMA + C stores).
// Blocks 0..15 also compute k amax (redundant, L2-broadcast) + pack 1/16 of
// the MFMA B-fragment buffer, overlapped with their x-load latency.
// pack[kstep*1024 + ntile*64 + lane] byte j: col=ntile*16+(lane&15),
//                                            k = kstep*32+(lane>>4)*8+j
// ---------------------------------------------------------------------------
__global__ __launch_bounds__(256, 2) void fused_kernel(
    const float* __restrict__ x, const float* __restrict__ kin,
    const float* __restrict__ input_scale, const float* __restrict__ kernel_scale,
    float* __restrict__ C, float* __restrict__ partials,
    float* __restrict__ kamaxf, ll* __restrict__ pack,
    unsigned* __restrict__ ctr) {
    __shared__ float sm[4];
    __shared__ char lds[128 * 256];  // 32 KB fp8 x-tile (swizzled)

    int tid = threadIdx.x;
    int lane = tid & 63, w = tid >> 6;
    int kg = lane >> 4, r16 = lane & 15;
    unsigned bid = blockIdx.x;

    // (1) pin this block's 128x256 x-slice into 128 VGPRs, fully coalesced.
    const float* xt = x + (size_t)bid * 128 * 256;
    f32x4 raw[32];
    #pragma unroll
    for (int i = 0; i < 32; ++i) {
        const float* p = xt + i * 1024 + tid * 4;
        asm volatile("global_load_dwordx4 %0, %1, off"
                     : "=v"(raw[i]) : "v"(p) : "memory");
    }

    // (2) k duty (blocks 0..15): overlaps the x-load latency. Compiler waits
    // for its own k loads are merely over-strong w.r.t. our asm loads (safe).
    if (bid < KBLK) {
        const f32x4* p = (const f32x4*)kin;
        float m = 0.0f;
        #pragma unroll 8
        for (int t = 0; t < 64; ++t) m = amax4(p[tid + t * 256], m);
        #pragma unroll
        for (int off = 32; off; off >>= 1) m = fmaxf(m, __shfl_down(m, off, 64));
        if (lane == 0) sm[w] = m;
        __syncthreads();
        float am = fmaxf(fmaxf(sm[0], sm[1]), fmaxf(sm[2], sm[3]));
        if (tid == 0) kamaxf[0] = am;  // all 16 write the same value
        float sf = scale_factor(am, kernel_scale[0]);
        #pragma unroll
        for (int ii = 0; ii < 2; ++ii) {
            int t = ((int)bid * 2 + ii) * 256 + tid;
            int l = t & 63, nt = (t >> 6) & 15, kstep = t >> 10;
            int col = nt * 16 + (l & 15);
            int k0 = kstep * 32 + (l >> 4) * 8;
            float v[8];
            #pragma unroll
            for (int j = 0; j < 8; ++j)
                v[j] = kin[(k0 + j) * 256 + col] * sf;  // |v|<=448(1+eps): RTNE->448
            unsigned lo = pack4_fp8(v[0], v[1], v[2], v[3]);
            unsigned hi = pack4_fp8(v[4], v[5], v[6], v[7]);
            pack[t] = (ll)lo | ((ll)hi << 32);
        }
        __threadfence();
        __syncthreads();
        if (tid == 0)
            __hip_atomic_fetch_add(ctr, 1u, __ATOMIC_RELEASE,
                                   __HIP_MEMORY_SCOPE_AGENT);
        __syncthreads();  // sm[] reused below
    }

    // (3) local x amax from the pinned regs.
    asm volatile("s_waitcnt vmcnt(0)" ::: "memory");
    __builtin_amdgcn_sched_barrier(0);
    float m = 0.0f;
    #pragma unroll
    for (int i = 0; i < 32; ++i) m = amax4(raw[i], m);
    #pragma unroll
    for (int off = 32; off; off >>= 1) m = fmaxf(m, __shfl_down(m, off, 64));
    if (lane == 0) sm[w] = m;
    __syncthreads();
    if (tid == 0) {
        partials[bid] = fmaxf(fmaxf(sm[0], sm[1]), fmaxf(sm[2], sm[3]));
        __threadfence();
        __hip_atomic_fetch_add(ctr, 1u, __ATOMIC_RELEASE,
                               __HIP_MEMORY_SCOPE_AGENT);
    }

    // (4) grid spin-barrier (all blocks co-resident by capacity: 512 = 2x256).
    if (tid == 0) {
        while (__hip_atomic_load(ctr, __ATOMIC_ACQUIRE,
                                 __HIP_MEMORY_SCOPE_AGENT) < CTR_TARGET)
            __builtin_amdgcn_s_sleep(2);
    }
    __syncthreads();
    __threadfence();  // acquire-side visibility for all threads

    // (5) global scales.
    const f32x4* pp = (const f32x4*)partials;
    float mm = 0.0f;
    #pragma unroll
    for (int i = 0; i < 2; ++i) mm = amax4(pp[lane + i * 64], mm);
    #pragma unroll
    for (int off = 32; off; off >>= 1) mm = fmaxf(mm, __shfl_xor(mm, off, 64));
    float sf_x = scale_factor(mm, input_scale[0]);
    float sf_k = scale_factor(kamaxf[0], kernel_scale[0]);
    float outscale = (1.0f / sf_x) * (1.0f / sf_k);

    // (6) quantize all raws in-register (frees 96 VGPRs).
    unsigned q[32];
    #pragma unroll
    for (int i = 0; i < 32; ++i)
        q[i] = pack4_fp8(raw[i].x * sf_x, raw[i].y * sf_x,
                         raw[i].z * sf_x, raw[i].w * sf_x);

    // (7) one LDS round-trip (XOR swizzle) + B-fragment preload.
    #pragma unroll
    for (int i = 0; i < 32; ++i) {
        int row = i * 4 + w;
        *(unsigned*)&lds[row * 256 + ((lane * 4) ^ ((row & 15) << 3))] = q[i];
    }
    ll Breg[32];  // [ks*4+j]
    #pragma unroll
    for (int i = 0; i < 32; ++i)
        Breg[i] = pack[(i >> 2) * 1024 + (w * 4 + (i & 3)) * 64 + lane];

    asm volatile("s_waitcnt lgkmcnt(0)" ::: "memory");
    __builtin_amdgcn_s_barrier();
    __builtin_amdgcn_sched_barrier(0);

    // (8) 4 tiles of 32 rows: fragment reads + MFMA + stores. No more barriers
    // (LDS is read-only from here).
    float* cb = C + (size_t)bid * 128 * 256 + w * 64;
    unsigned sw = (unsigned)(r16 << 3);
    #pragma unroll
    for (int t = 0; t < 4; ++t) {
        #pragma unroll
        for (int rg = 0; rg < 2; ++rg) {
            unsigned rbase = (unsigned)((t * 32 + rg * 16 + r16) * 256);
            ll A[8];
            #pragma unroll
            for (int ks = 0; ks < 8; ++ks)
                A[ks] = *(const ll*)&lds[rbase +
                        (((unsigned)(kg * 8 + ks * 32)) ^ sw)];
            f32x4 acc[4];
            #pragma unroll
            for (int j = 0; j < 4; ++j) acc[j] = (f32x4){0.f, 0.f, 0.f, 0.f};
            #pragma unroll
            for (int ks = 0; ks < 8; ++ks)
                #pragma unroll
                for (int j = 0; j < 4; ++j)
                    acc[j] = __builtin_amdgcn_mfma_f32_16x16x32_fp8_fp8(
                        A[ks], Breg[ks * 4 + j], acc[j], 0, 0, 0);
            // C/D layout: col = lane&15, row = (lane>>4)*4 + r
            int crow = t * 32 + rg * 16 + kg * 4;
            #pragma unroll
            for (int j = 0; j < 4; ++j)
                #pragma unroll
                for (int r = 0; r < 4; ++r)
                    cb[(size_t)(crow + r) * 256 + j * 16 + r16] =
                        acc[j][r] * outscale;
        }
    }
}

// ---------------------------------------------------------------------------
extern "C" void kernel_launch(void* const* d_in, const int* in_sizes, int n_in,
                              void* d_out, int out_size, void* d_ws, size_t ws_size,
                              hipStream_t stream) {
    const float* x = (const float*)d_in[0];             // [8,8192,256] f32
    const float* k = (const float*)d_in[1];             // [256,256] f32
    const float* input_scale = (const float*)d_in[2];   // [1]
    const float* kernel_scale = (const float*)d_in[3];  // [1]
    float* out = (float*)d_out;

    float* partials = (float*)d_ws;                     // [512]
    float* kamaxf = (float*)((char*)d_ws + 2048);       // [1]
    unsigned* ctr = (unsigned*)((char*)d_ws + 2056);    // [1] spin counter
    ll* pack = (ll*)((char*)d_ws + 16384);              // 64 KiB packed fp8 B

    // ws is NOT re-poisoned between replays: counter must be zeroed each call.
    hipMemsetAsync(ctr, 0, 4, stream);
    fused_kernel<<<GBLK, 256, 0, stream>>>(x, k, input_scale, kernel_scale,
                                           out, partials, kamaxf, pack, ctr);
}

// Round 10
// 179.629 us; speedup vs baseline: 1.4133x; 1.4133x over previous
//
#include <hip/hip_runtime.h>
#include <stdint.h>

#define FP8_MAX 448.0f
#define GBLK 512                 // 2 blocks/CU x 256 CU -> all co-resident
#define KBLK 64                  // blocks 0..63 also do k amax + pack slice
#define CTR_TARGET (GBLK + KBLK) // k-duty blocks increment twice

typedef __attribute__((ext_vector_type(4))) float f32x4;
typedef long long ll;

// flax fp8_ops.compute_scale: sf = fp8_max/amax with fallbacks (qdq multiplier).
__device__ __forceinline__ float scale_factor(float amax, float prev_scale) {
    float sf = FP8_MAX / amax;
    if (!(amax > 0.0f) || !isfinite(amax)) sf = 1.0f / prev_scale;
    return sf;
}

__device__ __forceinline__ unsigned pack4_fp8(float a, float b, float c, float d) {
    int v = __builtin_amdgcn_cvt_pk_fp8_f32(a, b, 0, false);
    v = __builtin_amdgcn_cvt_pk_fp8_f32(c, d, v, true);
    return (unsigned)v;
}

__device__ __forceinline__ float amax4(f32x4 v, float m) {
    float a0 = fmaxf(__builtin_fabsf(v.x), __builtin_fabsf(v.y));
    float a1 = fmaxf(__builtin_fabsf(v.z), __builtin_fabsf(v.w));
    return fmaxf(m, fmaxf(a0, a1));
}

// ---------------------------------------------------------------------------
// Fused, single launch. NO register stash across the barrier (R9 lesson:
// asm-pinned stashes crossing divergent code get spilled to scratch).
//   phase 0 (bid<KBLK): k amax (redundant, L2-broadcast) + pack 128 words of
//                       the MFMA B-fragment buffer; +1 on ctr.
//   phase 1: stream own 128x256 x-slice (plain loads), local amax ->
//            partials[bid]; +1 on ctr.  (Slice stays L2/L3-hot for phase 2.)
//   barrier: spin on ctr == 576 (all 512 blocks co-resident at 2/CU; spin
//            mechanism validated in R9).
//   phase 2: global scales -> R8-proven asm pipeline (3 raw buffers, counted
//            vmcnt) -> quant -> swizzled LDS (dbuf) -> SWAPPED mfma(B,A)
//            computing C^T fragments -> dwordx4 C stores (8/tile vs 32).
// pack[kstep*1024 + ntile*64 + lane] byte j: col=ntile*16+(lane&15),
//                                            k = kstep*32+(lane>>4)*8+j
// ---------------------------------------------------------------------------
#define ISSUE(RAW, t)                                                          \
    do {                                                                       \
        _Pragma("unroll")                                                      \
        for (int i = 0; i < 8; ++i) {                                          \
            const float* p = xt + (t) * 8192 + i * 1024 + tid * 4;             \
            asm volatile("global_load_dwordx4 %0, %1, off"                     \
                         : "=v"(RAW[i]) : "v"(p) : "memory");                  \
        }                                                                      \
    } while (0)

// Swapped-operand MFMA: D' = Bfrag x Afrag = C^T tile. Lane holds
// D'[n_local=(lane>>4)*4+r][m_local=lane&15]  ->  acc[j][r] =
// C[t*32+rg*16+r16][w*64 + j*16 + kg*4 + r]  ->  f32x4 store, 4 consec cols.
#define TILE(RAW, b, t)                                                        \
    do {                                                                       \
        _Pragma("unroll")                                                      \
        for (int i = 0; i < 8; ++i) {                                          \
            int row = i * 4 + w;                                               \
            unsigned v = pack4_fp8(RAW[i].x * sf_x, RAW[i].y * sf_x,           \
                                   RAW[i].z * sf_x, RAW[i].w * sf_x);          \
            *(unsigned*)&lds[b][row * 256 + ((lane * 4) ^ ((row & 15) << 3))] = v; \
        }                                                                      \
        asm volatile("s_waitcnt lgkmcnt(0)" ::: "memory");                     \
        __builtin_amdgcn_s_barrier();                                          \
        __builtin_amdgcn_sched_barrier(0);                                     \
        _Pragma("unroll")                                                      \
        for (int rg = 0; rg < 2; ++rg) {                                       \
            unsigned rbase = (unsigned)((rg * 16 + r16) * 256);                \
            ll A[8];                                                           \
            _Pragma("unroll")                                                  \
            for (int ks = 0; ks < 8; ++ks)                                     \
                A[ks] = *(const ll*)&lds[b][rbase +                            \
                        (((unsigned)(kg * 8 + ks * 32)) ^ sw)];                \
            f32x4 acc[4];                                                      \
            _Pragma("unroll")                                                  \
            for (int j = 0; j < 4; ++j) acc[j] = (f32x4){0.f, 0.f, 0.f, 0.f}; \
            _Pragma("unroll")                                                  \
            for (int ks = 0; ks < 8; ++ks)                                     \
                _Pragma("unroll")                                              \
                for (int j = 0; j < 4; ++j)                                    \
                    acc[j] = __builtin_amdgcn_mfma_f32_16x16x32_fp8_fp8(       \
                        Breg[ks * 4 + j], A[ks], acc[j], 0, 0, 0);             \
            _Pragma("unroll")                                                  \
            for (int j = 0; j < 4; ++j) {                                      \
                f32x4 o = acc[j] * outscale;                                   \
                *(f32x4*)&cb[(size_t)((t) * 32 + rg * 16 + r16) * 256 +        \
                             j * 16 + kg * 4] = o;                             \
            }                                                                  \
        }                                                                      \
    } while (0)

__global__ __launch_bounds__(256, 2) void fused_kernel(
    const float* __restrict__ x, const float* __restrict__ kin,
    const float* __restrict__ input_scale, const float* __restrict__ kernel_scale,
    float* __restrict__ C, float* __restrict__ partials,
    float* __restrict__ kamaxf, ll* __restrict__ pack,
    unsigned* __restrict__ ctr) {
    __shared__ float sm[4];
    __shared__ char lds[2][32 * 256];  // dbuf fp8 x-tiles

    int tid = threadIdx.x;
    int lane = tid & 63, w = tid >> 6;
    int kg = lane >> 4, r16 = lane & 15;
    unsigned bid = blockIdx.x;

    // ---- phase 0: k duty (blocks 0..63) ----
    if (bid < KBLK) {
        const f32x4* p = (const f32x4*)kin;
        float m = 0.0f;
        #pragma unroll 8
        for (int t = 0; t < 64; ++t) m = amax4(p[tid + t * 256], m);
        #pragma unroll
        for (int off = 32; off; off >>= 1) m = fmaxf(m, __shfl_down(m, off, 64));
        if (lane == 0) sm[w] = m;
        __syncthreads();
        float am = fmaxf(fmaxf(sm[0], sm[1]), fmaxf(sm[2], sm[3]));
        if (tid == 0) kamaxf[0] = am;  // all KBLK blocks write the same value
        float sf = scale_factor(am, kernel_scale[0]);
        if (tid < 128) {
            int t = (int)bid * 128 + tid;
            int l = t & 63, nt = (t >> 6) & 15, kstep = t >> 10;
            int col = nt * 16 + (l & 15);
            int k0 = kstep * 32 + (l >> 4) * 8;
            float v[8];
            #pragma unroll
            for (int j = 0; j < 8; ++j)
                v[j] = kin[(k0 + j) * 256 + col] * sf;  // |v|<=448(1+eps): RTNE->448
            unsigned lo = pack4_fp8(v[0], v[1], v[2], v[3]);
            unsigned hi = pack4_fp8(v[4], v[5], v[6], v[7]);
            pack[t] = (ll)lo | ((ll)hi << 32);
        }
        __threadfence();
        __syncthreads();
        if (tid == 0)
            __hip_atomic_fetch_add(ctr, 1u, __ATOMIC_RELEASE,
                                   __HIP_MEMORY_SCOPE_AGENT);
        __syncthreads();  // sm[] reused below
    }

    // ---- phase 1: stream own x-slice for local amax (no stash) ----
    const f32x4* xp = (const f32x4*)(x + (size_t)bid * 128 * 256);
    float m = 0.0f;
    #pragma unroll 8
    for (int i = 0; i < 32; ++i) m = amax4(xp[tid + i * 256], m);
    #pragma unroll
    for (int off = 32; off; off >>= 1) m = fmaxf(m, __shfl_down(m, off, 64));
    if (lane == 0) sm[w] = m;
    __syncthreads();
    if (tid == 0) {
        partials[bid] = fmaxf(fmaxf(sm[0], sm[1]), fmaxf(sm[2], sm[3]));
        __threadfence();
        __hip_atomic_fetch_add(ctr, 1u, __ATOMIC_RELEASE,
                               __HIP_MEMORY_SCOPE_AGENT);
    }

    // ---- grid spin-barrier (all 512 blocks co-resident; R9-validated) ----
    if (tid == 0) {
        while (__hip_atomic_load(ctr, __ATOMIC_ACQUIRE,
                                 __HIP_MEMORY_SCOPE_AGENT) < CTR_TARGET)
            __builtin_amdgcn_s_sleep(2);
    }
    __syncthreads();
    __threadfence();

    // ---- phase 2: scales, B fragments, pipelined GEMM ----
    const f32x4* pp = (const f32x4*)partials;
    float mm = 0.0f;
    #pragma unroll
    for (int i = 0; i < 2; ++i) mm = amax4(pp[lane + i * 64], mm);
    #pragma unroll
    for (int off = 32; off; off >>= 1) mm = fmaxf(mm, __shfl_xor(mm, off, 64));
    float sf_x = scale_factor(mm, input_scale[0]);
    float sf_k = scale_factor(kamaxf[0], kernel_scale[0]);
    float outscale = (1.0f / sf_x) * (1.0f / sf_k);

    ll Breg[32];  // [ks*4+j]
    #pragma unroll
    for (int i = 0; i < 32; ++i)
        Breg[i] = pack[(i >> 2) * 1024 + (w * 4 + (i & 3)) * 64 + lane];

    // Drain all compiler-visible memory ops so manual vmcnt counts are exact.
    asm volatile("s_waitcnt vmcnt(0) lgkmcnt(0)" ::: "memory");
    __builtin_amdgcn_sched_barrier(0);

    const float* xt = x + (size_t)bid * 128 * 256;
    float* cb = C + (size_t)bid * 128 * 256 + w * 64;
    unsigned sw = (unsigned)(r16 << 3);

    f32x4 raw0[8], raw1[8], raw2[8];
    ISSUE(raw0, 0);
    ISSUE(raw1, 1);
    ISSUE(raw2, 2);

    // t0: outstanding 24 -> drain raw0 only.
    asm volatile("s_waitcnt vmcnt(16)" ::: "memory");
    __builtin_amdgcn_sched_barrier(0);
    TILE(raw0, 0, 0);   // +8 stores

    // t1: queue raw1(8), raw2(8), stores0(8), raw3(8) -> drain raw1: vmcnt(24).
    ISSUE(raw0, 3);
    asm volatile("s_waitcnt vmcnt(24)" ::: "memory");
    __builtin_amdgcn_sched_barrier(0);
    TILE(raw1, 1, 1);   // +8 stores

    // t2: queue raw2(8), stores0(8), raw3(8), stores1(8) -> drain raw2: vmcnt(24).
    asm volatile("s_waitcnt vmcnt(24)" ::: "memory");
    __builtin_amdgcn_sched_barrier(0);
    TILE(raw2, 0, 2);   // +8 stores

    // t3: drain raw3; stores1+stores2 (16) stay in flight -> vmcnt(16).
    asm volatile("s_waitcnt vmcnt(16)" ::: "memory");
    __builtin_amdgcn_sched_barrier(0);
    TILE(raw0, 1, 3);
}

// ---------------------------------------------------------------------------
extern "C" void kernel_launch(void* const* d_in, const int* in_sizes, int n_in,
                              void* d_out, int out_size, void* d_ws, size_t ws_size,
                              hipStream_t stream) {
    const float* x = (const float*)d_in[0];             // [8,8192,256] f32
    const float* k = (const float*)d_in[1];             // [256,256] f32
    const float* input_scale = (const float*)d_in[2];   // [1]
    const float* kernel_scale = (const float*)d_in[3];  // [1]
    float* out = (float*)d_out;

    float* partials = (float*)d_ws;                     // [512]
    float* kamaxf = (float*)((char*)d_ws + 2048);       // [1]
    unsigned* ctr = (unsigned*)((char*)d_ws + 2056);    // [1] spin counter
    ll* pack = (ll*)((char*)d_ws + 16384);              // 64 KiB packed fp8 B

    // ws is NOT re-poisoned between replays: zero the counter every call.
    hipMemsetAsync(ctr, 0, 4, stream);
    fused_kernel<<<GBLK, 256, 0, stream>>>(x, k, input_scale, kernel_scale,
                                           out, partials, kamaxf, pack, ctr);
}

// Round 11
// 44.586 us; speedup vs baseline: 5.6939x; 4.0288x over previous
//
#include <hip/hip_runtime.h>
#include <stdint.h>

#define FP8_MAX 448.0f
#define KBLK 16   // prep blocks 0..15: k amax + pack
#define NXB 2048  // prep blocks 16..2063: x amax, 32 rows each (1:1 with gemm)

typedef __attribute__((ext_vector_type(4))) float f32x4;
typedef long long ll;

// flax fp8_ops.compute_scale: sf = fp8_max/amax with fallbacks (qdq multiplier).
__device__ __forceinline__ float scale_factor(float amax, float prev_scale) {
    float sf = FP8_MAX / amax;
    if (!(amax > 0.0f) || !isfinite(amax)) sf = 1.0f / prev_scale;
    return sf;
}

__device__ __forceinline__ unsigned pack4_fp8(float a, float b, float c, float d) {
    int v = __builtin_amdgcn_cvt_pk_fp8_f32(a, b, 0, false);
    v = __builtin_amdgcn_cvt_pk_fp8_f32(c, d, v, true);
    return (unsigned)v;
}

__device__ __forceinline__ float amax4(f32x4 v, float m) {
    float a0 = fmaxf(__builtin_fabsf(v.x), __builtin_fabsf(v.y));
    float a1 = fmaxf(__builtin_fabsf(v.z), __builtin_fabsf(v.w));
    return fmaxf(m, fmaxf(a0, a1));
}

// ---------------------------------------------------------------------------
// prep: blocks 0..15  -> EACH redundantly computes k amax (256KB, L2-shared)
//                       then packs 1/16 of the MFMA B-fragment buffer.
//       blocks 16..   -> x amax partials[xb] over rows [xb*32, xb*32+32)
//                       == gemm block xb's tile; (16+xb)%8 == xb%8 -> the
//                       gemm re-read hits the SAME XCD's L2.
// pack[kstep*1024 + ntile*64 + lane] byte j: col=ntile*16+(lane&15),
//                                            k = kstep*32+(lane>>4)*8+j
// ---------------------------------------------------------------------------
__global__ __launch_bounds__(256) void prep_kernel(
    const float* __restrict__ x, const float* __restrict__ k,
    const float* __restrict__ kernel_scale,
    float* __restrict__ partials, float* __restrict__ kamaxf,
    ll* __restrict__ pack) {
    __shared__ float sm[4];
    int tid = threadIdx.x;
    int lane = tid & 63, w = tid >> 6;

    if (blockIdx.x >= KBLK) {
        unsigned xb = blockIdx.x - KBLK;
        const f32x4* p = (const f32x4*)x + (size_t)xb * 2048;
        float m = 0.0f;
        #pragma unroll
        for (int t = 0; t < 8; ++t)
            m = amax4(p[tid + t * 256], m);
        #pragma unroll
        for (int off = 32; off; off >>= 1)
            m = fmaxf(m, __shfl_down(m, off, 64));
        if (lane == 0) sm[w] = m;
        __syncthreads();
        if (tid == 0)
            partials[xb] = fmaxf(fmaxf(sm[0], sm[1]), fmaxf(sm[2], sm[3]));
    } else {
        // ---- k amax (redundant per block; 256 KiB, L2-broadcast) ----
        const f32x4* p = (const f32x4*)k;
        float m = 0.0f;
        #pragma unroll 8
        for (int t = 0; t < 64; ++t)
            m = amax4(p[tid + t * 256], m);
        #pragma unroll
        for (int off = 32; off; off >>= 1)
            m = fmaxf(m, __shfl_down(m, off, 64));
        if (lane == 0) sm[w] = m;
        __syncthreads();
        float amax = fmaxf(fmaxf(sm[0], sm[1]), fmaxf(sm[2], sm[3]));
        if (tid == 0) kamaxf[0] = amax;  // all KBLK blocks write same value
        float sf = scale_factor(amax, kernel_scale[0]);
        // ---- pack this block's slice: 512 of 8192 words ----
        #pragma unroll
        for (int ii = 0; ii < 2; ++ii) {
            int t = (blockIdx.x * 2 + ii) * 256 + tid;
            int l = t & 63;
            int nt = (t >> 6) & 15;
            int kstep = t >> 10;
            int col = nt * 16 + (l & 15);
            int k0 = kstep * 32 + (l >> 4) * 8;
            float v[8];
            #pragma unroll
            for (int j = 0; j < 8; ++j)
                v[j] = k[(k0 + j) * 256 + col] * sf;  // |v|<=448(1+eps): RTNE->448
            unsigned lo = pack4_fp8(v[0], v[1], v[2], v[3]);
            unsigned hi = pack4_fp8(v[4], v[5], v[6], v[7]);
            pack[t] = (ll)lo | ((ll)hi << 32);
        }
    }
}

// ---------------------------------------------------------------------------
// GEMM: C[M,256] = qdq(x)[M,256] * qdq(k)[256,256] via fp8 MFMA.
// Grid 2048 x 32 rows (1:1, same-XCD with its prep block). 4 waves split N.
// Per block: compiler preamble (Breg + partials reduce + scales) -> full
// drain -> 8 pinned coalesced x-loads -> drain -> in-reg quant -> swizzled
// LDS -> one barrier -> 2 row-groups of {8 ds_read_b64, 32 SWAPPED MFMA
// (C^T fragments, R10-validated), 4 dwordx4 stores}. TLP (3 blocks/CU,
// 12 waves) hides latency; traffic is the binder.
// ---------------------------------------------------------------------------
__global__ __launch_bounds__(256, 3) void gemm_kernel(
    const float* __restrict__ x, const ll* __restrict__ Bpack,
    const float* __restrict__ partials, const float* __restrict__ kamaxf,
    const float* __restrict__ input_scale, const float* __restrict__ kernel_scale,
    float* __restrict__ C) {
    __shared__ char lds[32 * 256];  // 8 KB fp8 tile (swizzled)

    int tid = threadIdx.x;
    int w = tid >> 6;
    int lane = tid & 63;
    int kg = lane >> 4, r16 = lane & 15;
    unsigned sw = (unsigned)(r16 << 3);

    // ---- compiler-visible preamble ----
    ll Breg[32];  // [ks*4+j]
    #pragma unroll
    for (int i = 0; i < 32; ++i)
        Breg[i] = Bpack[(i >> 2) * 1024 + (w * 4 + (i & 3)) * 64 + lane];

    const f32x4* pp = (const f32x4*)partials;  // 2048 partials = 512 f32x4
    float m = 0.0f;
    #pragma unroll
    for (int i = 0; i < 8; ++i)
        m = amax4(pp[lane + i * 64], m);
    #pragma unroll
    for (int off = 32; off; off >>= 1)
        m = fmaxf(m, __shfl_xor(m, off, 64));
    float sf_x = scale_factor(m, input_scale[0]);
    float sf_k = scale_factor(kamaxf[0], kernel_scale[0]);
    float outscale = (1.0f / sf_x) * (1.0f / sf_k);

    // Drain everything compiler-visible so our manual waits are exact.
    asm volatile("s_waitcnt vmcnt(0) lgkmcnt(0)" ::: "memory");
    __builtin_amdgcn_sched_barrier(0);

    // ---- pinned coalesced x-load of this block's 32x256 tile ----
    const float* xt = x + (size_t)blockIdx.x * 32 * 256;
    f32x4 raw[8];
    #pragma unroll
    for (int i = 0; i < 8; ++i) {
        const float* p = xt + i * 1024 + tid * 4;
        asm volatile("global_load_dwordx4 %0, %1, off"
                     : "=v"(raw[i]) : "v"(p) : "memory");
    }
    asm volatile("s_waitcnt vmcnt(0)" ::: "memory");
    __builtin_amdgcn_sched_barrier(0);

    // ---- quant + swizzled LDS write ----
    #pragma unroll
    for (int i = 0; i < 8; ++i) {
        int row = i * 4 + w;  // bijective over 0..31
        unsigned v = pack4_fp8(raw[i].x * sf_x, raw[i].y * sf_x,
                               raw[i].z * sf_x, raw[i].w * sf_x);
        *(unsigned*)&lds[row * 256 + ((lane * 4) ^ ((row & 15) << 3))] = v;
    }
    asm volatile("s_waitcnt lgkmcnt(0)" ::: "memory");
    __builtin_amdgcn_s_barrier();
    __builtin_amdgcn_sched_barrier(0);

    // ---- compute: swapped mfma(B,A) -> C^T fragments -> dwordx4 stores ----
    // Lane holds D'[n_local=kg*4+r][m_local=r16] for n-tile j:
    //   C[row = rg*16 + r16][col = w*64 + j*16 + kg*4 + r]  -> f32x4 store.
    float* cb = C + (size_t)blockIdx.x * 32 * 256 + w * 64;
    #pragma unroll
    for (int rg = 0; rg < 2; ++rg) {
        unsigned rbase = (unsigned)((rg * 16 + r16) * 256);
        ll A[8];
        #pragma unroll
        for (int ks = 0; ks < 8; ++ks)
            A[ks] = *(const ll*)&lds[rbase + (((unsigned)(kg * 8 + ks * 32)) ^ sw)];

        f32x4 acc[4];
        #pragma unroll
        for (int j = 0; j < 4; ++j) acc[j] = (f32x4){0.f, 0.f, 0.f, 0.f};
        #pragma unroll
        for (int ks = 0; ks < 8; ++ks)
            #pragma unroll
            for (int j = 0; j < 4; ++j)
                acc[j] = __builtin_amdgcn_mfma_f32_16x16x32_fp8_fp8(
                    Breg[ks * 4 + j], A[ks], acc[j], 0, 0, 0);

        #pragma unroll
        for (int j = 0; j < 4; ++j) {
            f32x4 o = acc[j] * outscale;
            *(f32x4*)&cb[(size_t)(rg * 16 + r16) * 256 + j * 16 + kg * 4] = o;
        }
    }
}

// ---------------------------------------------------------------------------
extern "C" void kernel_launch(void* const* d_in, const int* in_sizes, int n_in,
                              void* d_out, int out_size, void* d_ws, size_t ws_size,
                              hipStream_t stream) {
    const float* x = (const float*)d_in[0];             // [8,8192,256] f32
    const float* k = (const float*)d_in[1];             // [256,256] f32
    const float* input_scale = (const float*)d_in[2];   // [1]
    const float* kernel_scale = (const float*)d_in[3];  // [1]
    float* out = (float*)d_out;

    float* partials = (float*)d_ws;                     // [2048]
    float* kamaxf = (float*)((char*)d_ws + 12288);      // [1]
    ll* pack = (ll*)((char*)d_ws + 16384);              // 64 KiB packed fp8 B

    int nx = in_sizes[0];                               // 16,777,216
    int M = nx / 256;                                   // 65,536 rows

    prep_kernel<<<NXB + KBLK, 256, 0, stream>>>(x, k, kernel_scale,
                                                partials, kamaxf, pack);
    gemm_kernel<<<M / 32, 256, 0, stream>>>(x, pack, partials, kamaxf,
                                            input_scale, kernel_scale, out);
}

// Round 12
// 44.281 us; speedup vs baseline: 5.7331x; 1.0069x over previous
//
#include <hip/hip_runtime.h>
#include <stdint.h>

#define FP8_MAX 448.0f
#define KBLK 16   // k amax+pack blocks (blockIdx 0..15)
#define NXB 2048  // x-amax blocks (blockIdx KBLK .. KBLK+NXB-1)

typedef __attribute__((ext_vector_type(4))) float f32x4;
typedef long long ll;

// flax fp8_ops.compute_scale: sf = fp8_max/amax with fallbacks (qdq multiplier).
__device__ __forceinline__ float scale_factor(float amax, float prev_scale) {
    float sf = FP8_MAX / amax;
    if (!(amax > 0.0f) || !isfinite(amax)) sf = 1.0f / prev_scale;
    return sf;
}

__device__ __forceinline__ unsigned pack4_fp8(float a, float b, float c, float d) {
    int v = __builtin_amdgcn_cvt_pk_fp8_f32(a, b, 0, false);
    v = __builtin_amdgcn_cvt_pk_fp8_f32(c, d, v, true);
    return (unsigned)v;
}

__device__ __forceinline__ float amax4(f32x4 v, float m) {
    float a0 = fmaxf(__builtin_fabsf(v.x), __builtin_fabsf(v.y));
    float a1 = fmaxf(__builtin_fabsf(v.z), __builtin_fabsf(v.w));
    return fmaxf(m, fmaxf(a0, a1));
}

// ---------------------------------------------------------------------------
// prep (R8-proven): blocks 0..KBLK-1 -> redundant k amax (256KB, L2-shared) +
//                   pack 1/KBLK of the MFMA B-fragment buffer.
//                   blocks KBLK..   -> x amax partials[NXB], grid-strided.
// pack[kstep*1024 + ntile*64 + lane] byte j: col=ntile*16+(lane&15),
//                                            k = kstep*32+(lane>>4)*8+j
// ---------------------------------------------------------------------------
__global__ __launch_bounds__(256) void prep_kernel(
    const float* __restrict__ x, const float* __restrict__ k,
    const float* __restrict__ kernel_scale,
    float* __restrict__ partials, float* __restrict__ kamaxf,
    ll* __restrict__ pack) {
    __shared__ float sm[4];
    int tid = threadIdx.x;
    int lane = tid & 63, w = tid >> 6;

    if (blockIdx.x >= KBLK) {
        const f32x4* p = (const f32x4*)x;
        unsigned base = (blockIdx.x - KBLK) * 256 + tid;
        float m = 0.0f;
        #pragma unroll
        for (int t = 0; t < 8; ++t)
            m = amax4(p[base + (unsigned)t * (NXB * 256)], m);
        #pragma unroll
        for (int off = 32; off; off >>= 1)
            m = fmaxf(m, __shfl_down(m, off, 64));
        if (lane == 0) sm[w] = m;
        __syncthreads();
        if (tid == 0)
            partials[blockIdx.x - KBLK] =
                fmaxf(fmaxf(sm[0], sm[1]), fmaxf(sm[2], sm[3]));
    } else {
        // ---- k amax (redundant per block; 256 KiB, L2-broadcast) ----
        const f32x4* p = (const f32x4*)k;
        float m = 0.0f;
        #pragma unroll 8
        for (int t = 0; t < 64; ++t)
            m = amax4(p[tid + t * 256], m);
        #pragma unroll
        for (int off = 32; off; off >>= 1)
            m = fmaxf(m, __shfl_down(m, off, 64));
        if (lane == 0) sm[w] = m;
        __syncthreads();
        float amax = fmaxf(fmaxf(sm[0], sm[1]), fmaxf(sm[2], sm[3]));
        if (tid == 0) kamaxf[0] = amax;  // all KBLK blocks write same value
        float sf = scale_factor(amax, kernel_scale[0]);
        // ---- pack this block's slice: 512 of 8192 words ----
        #pragma unroll
        for (int ii = 0; ii < 2; ++ii) {
            int t = (blockIdx.x * 2 + ii) * 256 + tid;
            int l = t & 63;
            int nt = (t >> 6) & 15;
            int kstep = t >> 10;
            int col = nt * 16 + (l & 15);
            int k0 = kstep * 32 + (l >> 4) * 8;
            float v[8];
            #pragma unroll
            for (int j = 0; j < 8; ++j)
                v[j] = k[(k0 + j) * 256 + col] * sf;  // |v|<=448(1+eps): RTNE->448
            unsigned lo = pack4_fp8(v[0], v[1], v[2], v[3]);
            unsigned hi = pack4_fp8(v[4], v[5], v[6], v[7]);
            pack[t] = (ll)lo | ((ll)hi << 32);
        }
    }
}

// ---------------------------------------------------------------------------
// GEMM (R8 pipeline + R10-validated C^T stores):
// Grid 512 (2 blocks/CU), 4 tiles of 32 rows per block, depth-2 prefetch
// (3 register buffers). SWAPPED mfma(Bfrag, Afrag) produces C^T fragments:
// lane holds C[rg*16+r16][w*64 + j*16 + kg*4 .. +3] -> ONE dwordx4 store per
// n-tile (8 stores/tile instead of 32). vmcnt accounting (stores count!):
//   t0 wait: raw0(8),raw1(8),raw2(8) out -> drain raw0: vmcnt(16)
//   t1 wait: raw1,raw2,st0(8),raw3 out   -> drain raw1: vmcnt(24)
//   t2 wait: raw2,st0,raw3,st1 out       -> drain raw2: vmcnt(24)
//   t3 wait: st0?,raw3,st1,st2 out       -> drain raw3: vmcnt(16)
// ---------------------------------------------------------------------------
#define ISSUE(RAW, t)                                                          \
    do {                                                                       \
        _Pragma("unroll")                                                      \
        for (int i = 0; i < 8; ++i) {                                          \
            const float* p = xt + (t) * 8192 + i * 1024 + tid * 4;             \
            asm volatile("global_load_dwordx4 %0, %1, off"                     \
                         : "=v"(RAW[i]) : "v"(p) : "memory");                  \
        }                                                                      \
    } while (0)

#define TILE(RAW, b, t)                                                        \
    do {                                                                       \
        _Pragma("unroll")                                                      \
        for (int i = 0; i < 8; ++i) {                                          \
            int row = i * 4 + w;                                               \
            unsigned v = pack4_fp8(RAW[i].x * sf_x, RAW[i].y * sf_x,           \
                                   RAW[i].z * sf_x, RAW[i].w * sf_x);          \
            *(unsigned*)&lds[b][row * 256 + ((lane * 4) ^ ((row & 15) << 3))] = v; \
        }                                                                      \
        asm volatile("s_waitcnt lgkmcnt(0)" ::: "memory");                     \
        __builtin_amdgcn_s_barrier();                                          \
        __builtin_amdgcn_sched_barrier(0);                                     \
        _Pragma("unroll")                                                      \
        for (int rg = 0; rg < 2; ++rg) {                                       \
            unsigned rbase = (unsigned)((rg * 16 + r16) * 256);                \
            ll A[8];                                                           \
            _Pragma("unroll")                                                  \
            for (int ks = 0; ks < 8; ++ks)                                     \
                A[ks] = *(const ll*)&lds[b][rbase +                            \
                        (((unsigned)(kg * 8 + ks * 32)) ^ sw)];                \
            f32x4 acc[4];                                                      \
            _Pragma("unroll")                                                  \
            for (int j = 0; j < 4; ++j) acc[j] = (f32x4){0.f, 0.f, 0.f, 0.f}; \
            _Pragma("unroll")                                                  \
            for (int ks = 0; ks < 8; ++ks)                                     \
                _Pragma("unroll")                                              \
                for (int j = 0; j < 4; ++j)                                    \
                    acc[j] = __builtin_amdgcn_mfma_f32_16x16x32_fp8_fp8(       \
                        Breg[ks * 4 + j], A[ks], acc[j], 0, 0, 0);             \
            _Pragma("unroll")                                                  \
            for (int j = 0; j < 4; ++j) {                                      \
                f32x4 o = acc[j] * outscale;                                   \
                *(f32x4*)&cb[(size_t)((t) * 32 + rg * 16 + r16) * 256 +        \
                             j * 16 + kg * 4] = o;                             \
            }                                                                  \
        }                                                                      \
    } while (0)

__global__ __launch_bounds__(256, 2) void gemm_kernel(
    const float* __restrict__ x, const ll* __restrict__ Bpack,
    const float* __restrict__ partials, const float* __restrict__ kamaxf,
    const float* __restrict__ input_scale, const float* __restrict__ kernel_scale,
    float* __restrict__ C) {
    __shared__ char lds[2][32 * 256];  // double-buffered fp8 tiles

    int tid = threadIdx.x;
    int w = tid >> 6;
    int lane = tid & 63;
    int kg = lane >> 4, r16 = lane & 15;
    unsigned sw = (unsigned)(r16 << 3);

    // Compiler-visible preamble (drained below so its waits can't interfere).
    ll Breg[32];  // [ks*4+j]
    #pragma unroll
    for (int i = 0; i < 32; ++i)
        Breg[i] = Bpack[(i >> 2) * 1024 + (w * 4 + (i & 3)) * 64 + lane];

    const f32x4* pp = (const f32x4*)partials;
    float m = 0.0f;
    #pragma unroll
    for (int i = 0; i < 8; ++i)
        m = amax4(pp[lane + i * 64], m);
    #pragma unroll
    for (int off = 32; off; off >>= 1)
        m = fmaxf(m, __shfl_xor(m, off, 64));
    float sf_x = scale_factor(m, input_scale[0]);
    float sf_k = scale_factor(kamaxf[0], kernel_scale[0]);
    float outscale = (1.0f / sf_x) * (1.0f / sf_k);

    asm volatile("s_waitcnt vmcnt(0) lgkmcnt(0)" ::: "memory");
    __builtin_amdgcn_sched_barrier(0);

    const float* xt = x + (size_t)blockIdx.x * 128 * 256;
    float* cb = C + (size_t)blockIdx.x * 128 * 256 + w * 64;

    f32x4 raw0[8], raw1[8], raw2[8];

    ISSUE(raw0, 0);
    ISSUE(raw1, 1);
    ISSUE(raw2, 2);

    // t0: outstanding 24 -> drain raw0 only.
    asm volatile("s_waitcnt vmcnt(16)" ::: "memory");
    __builtin_amdgcn_sched_barrier(0);
    TILE(raw0, 0, 0);   // +8 stores

    // t1: raw1(8), raw2(8), st0(8), raw3(8) -> drain raw1: vmcnt(24).
    ISSUE(raw0, 3);
    asm volatile("s_waitcnt vmcnt(24)" ::: "memory");
    __builtin_amdgcn_sched_barrier(0);
    TILE(raw1, 1, 1);   // +8 stores

    // t2: raw2(8), st0(8), raw3(8), st1(8) -> drain raw2: vmcnt(24).
    asm volatile("s_waitcnt vmcnt(24)" ::: "memory");
    __builtin_amdgcn_sched_barrier(0);
    TILE(raw2, 0, 2);   // +8 stores

    // t3: raw3(8), st1(8), st2(8) (st0 maybe done) -> drain raw3: vmcnt(16).
    asm volatile("s_waitcnt vmcnt(16)" ::: "memory");
    __builtin_amdgcn_sched_barrier(0);
    TILE(raw0, 1, 3);
}

// ---------------------------------------------------------------------------
extern "C" void kernel_launch(void* const* d_in, const int* in_sizes, int n_in,
                              void* d_out, int out_size, void* d_ws, size_t ws_size,
                              hipStream_t stream) {
    const float* x = (const float*)d_in[0];             // [8,8192,256] f32
    const float* k = (const float*)d_in[1];             // [256,256] f32
    const float* input_scale = (const float*)d_in[2];   // [1]
    const float* kernel_scale = (const float*)d_in[3];  // [1]
    float* out = (float*)d_out;

    float* partials = (float*)d_ws;                     // [2048]
    float* kamaxf = partials + 2048;                    // [1]
    ll* pack = (ll*)((char*)d_ws + 16384);              // 64 KiB packed fp8 B

    int nx = in_sizes[0];                               // 16,777,216
    int M = nx / 256;                                   // 65,536 rows

    prep_kernel<<<NXB + KBLK, 256, 0, stream>>>(x, k, kernel_scale,
                                                partials, kamaxf, pack);
    gemm_kernel<<<M / 128, 256, 0, stream>>>(x, pack, partials, kamaxf,
                                             input_scale, kernel_scale, out);
}

// Round 13
// 41.241 us; speedup vs baseline: 6.1558x; 1.0737x over previous
//
#include <hip/hip_runtime.h>
#include <stdint.h>

#define FP8_MAX 448.0f
#define KBLK 16   // prep blocks 0..15: k amax + pack
#define NXB 2048  // prep blocks 16..: x amax, slice-aligned with gemm blocks

typedef __attribute__((ext_vector_type(4))) float f32x4;
typedef long long ll;

// flax fp8_ops.compute_scale: sf = fp8_max/amax with fallbacks (qdq multiplier).
__device__ __forceinline__ float scale_factor(float amax, float prev_scale) {
    float sf = FP8_MAX / amax;
    if (!(amax > 0.0f) || !isfinite(amax)) sf = 1.0f / prev_scale;
    return sf;
}

__device__ __forceinline__ unsigned pack4_fp8(float a, float b, float c, float d) {
    int v = __builtin_amdgcn_cvt_pk_fp8_f32(a, b, 0, false);
    v = __builtin_amdgcn_cvt_pk_fp8_f32(c, d, v, true);
    return (unsigned)v;
}

__device__ __forceinline__ float amax4(f32x4 v, float m) {
    float a0 = fmaxf(__builtin_fabsf(v.x), __builtin_fabsf(v.y));
    float a1 = fmaxf(__builtin_fabsf(v.z), __builtin_fabsf(v.w));
    return fmaxf(m, fmaxf(a0, a1));
}

// ---------------------------------------------------------------------------
// prep (exact 41.1us R8 version): blocks 0..15 -> redundant k amax (256KB,
// L2-broadcast) + pack 1/16 of B fragments. blocks 16.. -> x amax partials,
// slice-aligned: block 16+xb reads gemm-block (xb>>2)'s rows, quarter (xb&3).
// pack[kstep*1024 + ntile*64 + lane] byte j: col=ntile*16+(lane&15),
//                                            k = kstep*32+(lane>>4)*8+j
// ---------------------------------------------------------------------------
__global__ __launch_bounds__(256) void prep_kernel(
    const float* __restrict__ x, const float* __restrict__ k,
    const float* __restrict__ kernel_scale,
    float* __restrict__ partials, float* __restrict__ kamaxf,
    ll* __restrict__ pack) {
    __shared__ float sm[4];
    int tid = threadIdx.x;
    int lane = tid & 63, w = tid >> 6;

    if (blockIdx.x >= KBLK) {
        unsigned xb = blockIdx.x - KBLK;
        const f32x4* p = (const f32x4*)x;
        unsigned base = (xb >> 2) * 8192 + (xb & 3) * 2048 + tid;
        float m = 0.0f;
        #pragma unroll
        for (int t = 0; t < 8; ++t)
            m = amax4(p[base + (unsigned)t * 256], m);
        #pragma unroll
        for (int off = 32; off; off >>= 1)
            m = fmaxf(m, __shfl_down(m, off, 64));
        if (lane == 0) sm[w] = m;
        __syncthreads();
        if (tid == 0)
            partials[xb] = fmaxf(fmaxf(sm[0], sm[1]), fmaxf(sm[2], sm[3]));
    } else {
        // ---- k amax (redundant per block; 256 KiB, L2-broadcast) ----
        const f32x4* p = (const f32x4*)k;
        float m = 0.0f;
        #pragma unroll 8
        for (int t = 0; t < 64; ++t)
            m = amax4(p[tid + t * 256], m);
        #pragma unroll
        for (int off = 32; off; off >>= 1)
            m = fmaxf(m, __shfl_down(m, off, 64));
        if (lane == 0) sm[w] = m;
        __syncthreads();
        float amax = fmaxf(fmaxf(sm[0], sm[1]), fmaxf(sm[2], sm[3]));
        if (tid == 0) kamaxf[0] = amax;  // all KBLK blocks write same value
        float sf = scale_factor(amax, kernel_scale[0]);
        // ---- pack this block's slice: 512 of 8192 words ----
        #pragma unroll
        for (int ii = 0; ii < 2; ++ii) {
            int t = (blockIdx.x * 2 + ii) * 256 + tid;
            int l = t & 63;
            int nt = (t >> 6) & 15;
            int kstep = t >> 10;
            int col = nt * 16 + (l & 15);
            int k0 = kstep * 32 + (l >> 4) * 8;
            float v[8];
            #pragma unroll
            for (int j = 0; j < 8; ++j)
                v[j] = k[(k0 + j) * 256 + col] * sf;  // |v|<=448(1+eps): RTNE->448
            unsigned lo = pack4_fp8(v[0], v[1], v[2], v[3]);
            unsigned hi = pack4_fp8(v[4], v[5], v[6], v[7]);
            pack[t] = (ll)lo | ((ll)hi << 32);
        }
    }
}

// ---------------------------------------------------------------------------
// GEMM = R8 base (depth-2 counted-vmcnt pipeline, mfma(A,B)) with ONE change:
// the epilogue transposes each wave's 16x64 C-tile through a per-wave LDS
// scratch ([16][68] f32, stride 68 -> 2-way bank aliasing = free, same-wave
// RAW so NO barrier) and stores f32x4 per lane covering 4 rows x 256B fully
// CONTIGUOUS segments per instruction (was 64B segments).
// Store count/tile: 8 dwordx4. vmcnt accounting (stores count!):
//   t0: raw0,raw1,raw2 out          -> drain raw0: vmcnt(16)
//   t1: raw1,raw2,st0(8),raw3 out   -> drain raw1: vmcnt(24)
//   t2: raw2,st0,raw3,st1 out       -> drain raw2: vmcnt(24)
//   t3: st0?,raw3,st1,st2 out       -> drain raw3: vmcnt(16)
// ---------------------------------------------------------------------------
#define ISSUE(RAW, t)                                                          \
    do {                                                                       \
        _Pragma("unroll")                                                      \
        for (int i = 0; i < 8; ++i) {                                          \
            const float* p = xt + (t) * 8192 + i * 1024 + tid * 4;             \
            asm volatile("global_load_dwordx4 %0, %1, off"                     \
                         : "=v"(RAW[i]) : "v"(p) : "memory");                  \
        }                                                                      \
    } while (0)

#define TILE(RAW, b, t)                                                        \
    do {                                                                       \
        _Pragma("unroll")                                                      \
        for (int i = 0; i < 8; ++i) {                                          \
            int row = i * 4 + w;                                               \
            unsigned v = pack4_fp8(RAW[i].x * sf_x, RAW[i].y * sf_x,           \
                                   RAW[i].z * sf_x, RAW[i].w * sf_x);          \
            *(unsigned*)&lds[b][row * 256 + ((lane * 4) ^ ((row & 15) << 3))] = v; \
        }                                                                      \
        asm volatile("s_waitcnt lgkmcnt(0)" ::: "memory");                     \
        __builtin_amdgcn_s_barrier();                                          \
        __builtin_amdgcn_sched_barrier(0);                                     \
        _Pragma("unroll")                                                      \
        for (int rg = 0; rg < 2; ++rg) {                                       \
            unsigned rbase = (unsigned)((rg * 16 + r16) * 256);                \
            ll A[8];                                                           \
            _Pragma("unroll")                                                  \
            for (int ks = 0; ks < 8; ++ks)                                     \
                A[ks] = *(const ll*)&lds[b][rbase +                            \
                        (((unsigned)(kg * 8 + ks * 32)) ^ sw)];                \
            f32x4 acc[4];                                                      \
            _Pragma("unroll")                                                  \
            for (int j = 0; j < 4; ++j) acc[j] = (f32x4){0.f, 0.f, 0.f, 0.f}; \
            _Pragma("unroll")                                                  \
            for (int ks = 0; ks < 8; ++ks)                                     \
                _Pragma("unroll")                                              \
                for (int j = 0; j < 4; ++j)                                    \
                    acc[j] = __builtin_amdgcn_mfma_f32_16x16x32_fp8_fp8(       \
                        A[ks], Breg[ks * 4 + j], acc[j], 0, 0, 0);             \
            /* transpose 16x64 wave-tile via private LDS: no barrier (same-  */\
            /* wave RAW; compiler inserts lgkmcnt). acc[j][r] = C[kg*4+r]    */\
            /* [j*16+r16] within the tile.                                   */\
            _Pragma("unroll")                                                  \
            for (int j = 0; j < 4; ++j)                                        \
                _Pragma("unroll")                                              \
                for (int r = 0; r < 4; ++r)                                    \
                    trw[(kg * 4 + r) * 68 + j * 16 + r16] =                    \
                        acc[j][r] * outscale;                                  \
            _Pragma("unroll")                                                  \
            for (int rr = 0; rr < 4; ++rr) {                                   \
                f32x4 o = *(const f32x4*)&trw[(rr * 4 + kg) * 68 + r16 * 4];   \
                *(f32x4*)&cb[(size_t)(t) * 8192 +                              \
                             (size_t)(rg * 16 + rr * 4 + kg) * 256 +           \
                             r16 * 4] = o;                                     \
            }                                                                  \
        }                                                                      \
    } while (0)

__global__ __launch_bounds__(256, 2) void gemm_kernel(
    const float* __restrict__ x, const ll* __restrict__ Bpack,
    const float* __restrict__ partials, const float* __restrict__ kamaxf,
    const float* __restrict__ input_scale, const float* __restrict__ kernel_scale,
    float* __restrict__ C) {
    __shared__ char lds[2][32 * 256];   // double-buffered fp8 x-tiles
    __shared__ float tr[4][16 * 68];    // per-wave C-transpose scratch

    int tid = threadIdx.x;
    int w = tid >> 6;
    int lane = tid & 63;
    int kg = lane >> 4, r16 = lane & 15;
    unsigned sw = (unsigned)(r16 << 3);
    float* trw = tr[w];

    // Compiler-visible preamble (drained below so its waits can't interfere).
    ll Breg[32];  // [ks*4+j]
    #pragma unroll
    for (int i = 0; i < 32; ++i)
        Breg[i] = Bpack[(i >> 2) * 1024 + (w * 4 + (i & 3)) * 64 + lane];

    const f32x4* pp = (const f32x4*)partials;
    float m = 0.0f;
    #pragma unroll
    for (int i = 0; i < 8; ++i)
        m = amax4(pp[lane + i * 64], m);
    #pragma unroll
    for (int off = 32; off; off >>= 1)
        m = fmaxf(m, __shfl_xor(m, off, 64));
    float sf_x = scale_factor(m, input_scale[0]);
    float sf_k = scale_factor(kamaxf[0], kernel_scale[0]);
    float outscale = (1.0f / sf_x) * (1.0f / sf_k);

    asm volatile("s_waitcnt vmcnt(0) lgkmcnt(0)" ::: "memory");
    __builtin_amdgcn_sched_barrier(0);

    const float* xt = x + (size_t)blockIdx.x * 128 * 256;
    float* cb = C + (size_t)blockIdx.x * 128 * 256 + w * 64;

    f32x4 raw0[8], raw1[8], raw2[8];

    ISSUE(raw0, 0);
    ISSUE(raw1, 1);
    ISSUE(raw2, 2);

    // t0: outstanding 24 -> drain raw0 only.
    asm volatile("s_waitcnt vmcnt(16)" ::: "memory");
    __builtin_amdgcn_sched_barrier(0);
    TILE(raw0, 0, 0);   // +8 stores

    // t1: raw1(8), raw2(8), st0(8), raw3(8) -> drain raw1: vmcnt(24).
    ISSUE(raw0, 3);
    asm volatile("s_waitcnt vmcnt(24)" ::: "memory");
    __builtin_amdgcn_sched_barrier(0);
    TILE(raw1, 1, 1);   // +8 stores

    // t2: raw2(8), st0(8), raw3(8), st1(8) -> drain raw2: vmcnt(24).
    asm volatile("s_waitcnt vmcnt(24)" ::: "memory");
    __builtin_amdgcn_sched_barrier(0);
    TILE(raw2, 0, 2);   // +8 stores

    // t3: raw3(8), st1(8), st2(8) (st0 maybe done) -> drain raw3: vmcnt(16).
    asm volatile("s_waitcnt vmcnt(16)" ::: "memory");
    __builtin_amdgcn_sched_barrier(0);
    TILE(raw0, 1, 3);
}

// ---------------------------------------------------------------------------
extern "C" void kernel_launch(void* const* d_in, const int* in_sizes, int n_in,
                              void* d_out, int out_size, void* d_ws, size_t ws_size,
                              hipStream_t stream) {
    const float* x = (const float*)d_in[0];             // [8,8192,256] f32
    const float* k = (const float*)d_in[1];             // [256,256] f32
    const float* input_scale = (const float*)d_in[2];   // [1]
    const float* kernel_scale = (const float*)d_in[3];  // [1]
    float* out = (float*)d_out;

    float* partials = (float*)d_ws;                     // [2048]
    float* kamaxf = partials + 2048;                    // [1]
    ll* pack = (ll*)((char*)d_ws + 16384);              // 64 KiB packed fp8 B

    int nx = in_sizes[0];                               // 16,777,216
    int M = nx / 256;                                   // 65,536 rows

    prep_kernel<<<NXB + KBLK, 256, 0, stream>>>(x, k, kernel_scale,
                                                partials, kamaxf, pack);
    gemm_kernel<<<M / 128, 256, 0, stream>>>(x, pack, partials, kamaxf,
                                             input_scale, kernel_scale, out);
}